// Round 7
// baseline (210.095 us; speedup 1.0000x reference)
//
#include <hip/hip_runtime.h>

// Ragged gather-to-padded for SparseConvUnet preprocessing.
// feature: [Nrows, 128] f32 packed; atom_num: [N] int32 in [0,14);
// out = concat( padded [N,14,128] f32 (zero where slot>=atom_num), label as f32 [N] ).
//
// R7: single-variable A/B vs R6 — GBLOCKS 512 -> 256 (1 block/CU, 256
// concurrent write streams, ~29 MB moving front). Everything else identical.

#define MAX_ATOMS 14
#define F4_PER_ROW 32                       // 128 floats = 32 float4
#define F4_PER_RES (MAX_ATOMS * F4_PER_ROW) // 448 = 7 * 64
#define TILE 16                             // residues per block-iteration (= waves/block)
#define GBLOCKS 256
#define GTHREADS 1024

typedef float f32x4 __attribute__((ext_vector_type(4)));

// ---- kernel A: per-256-residue chunk sums ----
__global__ __launch_bounds__(256) void k_sums(const int* __restrict__ atom_num,
                                              int n, int* __restrict__ sums) {
    __shared__ int lds[256];
    int t = threadIdx.x;
    int r = blockIdx.x * 256 + t;
    lds[t] = (r < n) ? atom_num[r] : 0;
    __syncthreads();
    for (int d = 128; d > 0; d >>= 1) {
        if (t < d) lds[t] += lds[t + d];
        __syncthreads();
    }
    if (t == 0) sums[blockIdx.x] = lds[0];
}

// ---- kernel B: per-residue offsets + label cast ----
__global__ __launch_bounds__(256) void k_prep(const int* __restrict__ atom_num,
                                              const int* __restrict__ sums,
                                              const int* __restrict__ label,
                                              int n,
                                              int* __restrict__ offsets,
                                              float* __restrict__ out_label) {
    __shared__ int red[256];
    __shared__ int scn[256];
    int t = threadIdx.x;
    int b = blockIdx.x;
    // base = sum sums[0..b)  (L2-hot, <=2 strided loads + tree reduce)
    int part = 0;
    for (int j = t; j < b; j += 256) part += sums[j];
    red[t] = part;
    __syncthreads();
    for (int d = 128; d > 0; d >>= 1) {
        if (t < d) red[t] += red[t + d];
        __syncthreads();
    }
    int base = red[0];
    // exclusive scan of this chunk's atom_num
    int r = b * 256 + t;
    int v = (r < n) ? atom_num[r] : 0;
    scn[t] = v;
    __syncthreads();
    for (int d = 1; d < 256; d <<= 1) {
        int add = (t >= d) ? scn[t - d] : 0;
        __syncthreads();
        scn[t] += add;
        __syncthreads();
    }
    if (r < n) {
        offsets[r] = base + scn[t] - v;
        out_label[r] = (float)label[r];     // harness reads d_out as f32
    }
}

// ---- kernel C: pure streaming gather, fully resident, lockstep front ----
__global__ __launch_bounds__(GTHREADS, 8) void k_gather(
        const f32x4* __restrict__ feat,
        const int* __restrict__ atom_num,
        const int* __restrict__ offsets,
        f32x4* __restrict__ out,
        int n, int ntiles) {
    int w       = threadIdx.x >> 6;        // wave 0..15
    int lane    = threadIdx.x & 63;
    int halfrow = lane >> 5;               // which row of the lane's pair

    for (int tile = blockIdx.x; tile < ntiles; tile += GBLOCKS) {
        int r = tile * TILE + w;           // one residue per wave
        if (r < n) {
            int off = offsets[r];          // wave-uniform broadcast load (L2-hot)
            int cnt = atom_num[r];
            const f32x4* fp = feat + (size_t)off * F4_PER_ROW + lane;
            f32x4* op = out + (size_t)r * F4_PER_RES + lane;
            #pragma unroll
            for (int i = 0; i < 7; ++i) {
                f32x4 v = (f32x4)0.f;
                if (2 * i + halfrow < cnt)
                    v = __builtin_nontemporal_load(fp + i * 64);
                __builtin_nontemporal_store(v, op + i * 64);
            }
        }
    }
}

extern "C" void kernel_launch(void* const* d_in, const int* in_sizes, int n_in,
                              void* d_out, int out_size, void* d_ws, size_t ws_size,
                              hipStream_t stream) {
    const float* feature = (const float*)d_in[0];
    const int* atom_num  = (const int*)d_in[1];
    const int* label     = (const int*)d_in[2];
    const int n = in_sizes[1];               // N_res = 100000

    float* out = (float*)d_out;
    float* out_label = out + (size_t)n * MAX_ATOMS * 128;

    int nb = (n + 255) / 256;                // 391
    int* ws_sums    = (int*)d_ws;            // nb ints
    int* ws_offsets = ws_sums + nb;          // n ints

    k_sums<<<nb, 256, 0, stream>>>(atom_num, n, ws_sums);
    k_prep<<<nb, 256, 0, stream>>>(atom_num, ws_sums, label, n,
                                   ws_offsets, out_label);

    int ntiles = (n + TILE - 1) / TILE;      // 6250
    k_gather<<<GBLOCKS, GTHREADS, 0, stream>>>(
        (const f32x4*)feature, atom_num, ws_offsets,
        (f32x4*)out, n, ntiles);
}